// Round 1
// baseline (235.633 us; speedup 1.0000x reference)
//
#include <hip/hip_runtime.h>
#include <hip/hip_bf16.h>
#include <math.h>

#define S_LEN   4096
#define DMODEL  1024
#define NAX     72
#define NPAR    12
#define NCOL    864      // NPAR*NAX
#define TPROP   600
#define LN_EPS  1e-5f

// ---------------- Kernel 1: LayerNorm (fp32) ----------------
// 1 block (256 thr) per row; each thread 1 float4.
__global__ __launch_bounds__(256) void k_layernorm(
    const float* __restrict__ x, const float* __restrict__ gamma,
    const float* __restrict__ beta, float* __restrict__ h)
{
    int row = blockIdx.x;
    int tid = threadIdx.x;
    const float4* xr = (const float4*)(x + (size_t)row * DMODEL);
    float4 v = xr[tid];
    float s  = v.x + v.y + v.z + v.w;
    float sq = v.x*v.x + v.y*v.y + v.z*v.z + v.w*v.w;
    #pragma unroll
    for (int off = 1; off < 64; off <<= 1) {
        s  += __shfl_xor(s, off);
        sq += __shfl_xor(sq, off);
    }
    __shared__ float ls[4], lq[4];
    int wid = tid >> 6, lane = tid & 63;
    if (lane == 0) { ls[wid] = s; lq[wid] = sq; }
    __syncthreads();
    s  = ls[0] + ls[1] + ls[2] + ls[3];
    sq = lq[0] + lq[1] + lq[2] + lq[3];
    float mu  = s * (1.f / DMODEL);
    float var = sq * (1.f / DMODEL) - mu * mu;
    float rs  = rsqrtf(var + LN_EPS);
    float4 g = ((const float4*)gamma)[tid];
    float4 b = ((const float4*)beta)[tid];
    float4 o;
    o.x = (v.x - mu) * rs * g.x + b.x;
    o.y = (v.y - mu) * rs * g.y + b.y;
    o.z = (v.z - mu) * rs * g.z + b.z;
    o.w = (v.w - mu) * rs * g.w + b.w;
    ((float4*)(h + (size_t)row * DMODEL))[tid] = o;
}

// ---------------- Kernel 2: GEMM P = h @ W^T + b (fp32 vector) ----------------
// Tile 128x64, BK=16, 256 threads, per-thread 8x4.
__global__ __launch_bounds__(256) void k_gemm(
    const float* __restrict__ h, const float* __restrict__ W,
    const float* __restrict__ bias, float* __restrict__ P)
{
    __shared__ float As[16][132];
    __shared__ float Bs[16][68];
    int tid = threadIdx.x;
    int n0 = blockIdx.x * 64;
    int m0 = blockIdx.y * 128;
    int ar = tid >> 2, ac = tid & 3;         // staging map
    int tm = tid & 15, tn = tid >> 4;        // compute map
    float acc[8][4];
    #pragma unroll
    for (int r = 0; r < 8; ++r)
        #pragma unroll
        for (int c = 0; c < 4; ++c) acc[r][c] = 0.f;

    const float* gA0 = h + (size_t)(m0 + ar) * DMODEL + ac * 4;
    const float* gA1 = gA0 + (size_t)64 * DMODEL;
    int brow = n0 + ar;
    bool bok = brow < NCOL;
    const float* gB = W + (size_t)(bok ? brow : 0) * DMODEL + ac * 4;

    for (int k0 = 0; k0 < DMODEL; k0 += 16) {
        float4 va = *(const float4*)(gA0 + k0);
        float4 vb = *(const float4*)(gA1 + k0);
        float4 vw = bok ? *(const float4*)(gB + k0) : make_float4(0.f,0.f,0.f,0.f);
        __syncthreads();   // previous compute done before overwriting LDS
        As[ac*4+0][ar]    = va.x; As[ac*4+1][ar]    = va.y;
        As[ac*4+2][ar]    = va.z; As[ac*4+3][ar]    = va.w;
        As[ac*4+0][ar+64] = vb.x; As[ac*4+1][ar+64] = vb.y;
        As[ac*4+2][ar+64] = vb.z; As[ac*4+3][ar+64] = vb.w;
        Bs[ac*4+0][ar] = vw.x; Bs[ac*4+1][ar] = vw.y;
        Bs[ac*4+2][ar] = vw.z; Bs[ac*4+3][ar] = vw.w;
        __syncthreads();
        #pragma unroll
        for (int k = 0; k < 16; ++k) {
            float4 a0 = *(const float4*)&As[k][tm*8];
            float4 a1 = *(const float4*)&As[k][tm*8+4];
            float4 b4 = *(const float4*)&Bs[k][tn*4];
            float av[8] = {a0.x,a0.y,a0.z,a0.w,a1.x,a1.y,a1.z,a1.w};
            float bv[4] = {b4.x,b4.y,b4.z,b4.w};
            #pragma unroll
            for (int r = 0; r < 8; ++r)
                #pragma unroll
                for (int c = 0; c < 4; ++c)
                    acc[r][c] = fmaf(av[r], bv[c], acc[r][c]);
        }
    }
    int nbase = n0 + tn * 4;
    if (nbase < NCOL) {
        float4 bb = *(const float4*)(bias + nbase);
        #pragma unroll
        for (int r = 0; r < 8; ++r) {
            int m = m0 + tm * 8 + r;
            float4 o;
            o.x = acc[r][0] + bb.x; o.y = acc[r][1] + bb.y;
            o.z = acc[r][2] + bb.z; o.w = acc[r][3] + bb.w;
            *(float4*)(P + (size_t)m * NCOL + nbase) = o;
        }
    }
}

// ---------------- Kernel 3: param transforms + tail outputs ----------------
__device__ __forceinline__ float softplus_f(float x) {
    return fmaxf(x, 0.f) + log1pf(expf(-fabsf(x)));
}

__global__ __launch_bounds__(256) void k_params(
    const float* __restrict__ P, float* __restrict__ params,
    float* __restrict__ out)
{
    int g = blockIdx.x * 256 + threadIdx.x;
    if (g >= S_LEN * NAX) return;
    int s = g / NAX, a = g - s * NAX;
    const float* pr = P + (size_t)s * NCOL + a;
    float p0  = pr[0*NAX], p1  = pr[1*NAX], p2  = pr[2*NAX], p3  = pr[3*NAX];
    float p4  = pr[4*NAX], p5  = pr[5*NAX], p6  = pr[6*NAX], p7  = pr[7*NAX];
    float p8  = pr[8*NAX], p9  = pr[9*NAX], p10 = pr[10*NAX], p11 = pr[11*NAX];

    float d  = softplus_f(p1), hd  = 0.5f * d;
    float w  = sqrtf(softplus_f(p0));
    float A  = 2.f * expf(-hd) * cosf(w);
    float B  = expf(-d);
    float d2 = softplus_f(p3), hd2 = 0.5f * d2;
    float w2 = sqrtf(softplus_f(p2));
    float A2 = 2.f * expf(-hd2) * cosf(w2);
    float B2 = expf(-d2);

    float4* pp = (float4*)(params + ((size_t)a * S_LEN + s) * 12);
    pp[0] = make_float4(A,  B,  p4, hd);
    pp[1] = make_float4(w,  p6, A2, B2);
    pp[2] = make_float4(p5, hd2, w2, p7);

    size_t o1 = (size_t)NAX * S_LEN;
    float* o = out + (size_t)a * S_LEN + s;
    o[1*o1] = p8;
    o[2*o1] = softplus_f(p9);
    o[3*o1] = p10;
    o[4*o1] = softplus_f(p11);
}

// ---------------- Kernel 4: damped-oscillator scan + anti-diagonal sum ----------------
// block = 1 wave (64 thr); block (tile,axis) owns output positions [P0,P0+64) of axis a.
// Each lane handles 11 sources; 2nd-order recurrence per oscillator; register acc[64].
__global__ __launch_bounds__(64) void k_scan(
    const float* __restrict__ params, float* __restrict__ out)
{
    int a    = blockIdx.y;
    int P0   = blockIdx.x * 64;
    int lane = threadIdx.x;
    float acc[64];
    #pragma unroll
    for (int i = 0; i < 64; ++i) acc[i] = 0.f;

    const float* pbase = params + (size_t)a * S_LEN * 12;
    for (int j = 0; j < 11; ++j) {
        int s = P0 - 599 + j * 64 + lane;
        bool vs = (s >= 0) && (s <= P0 + 63);
        if (__ballot(vs) == 0ULL) continue;
        int sc = vs ? s : 0;
        const float4* pp = (const float4*)(pbase + (size_t)sc * 12);
        float4 q0 = pp[0], q1 = pp[1], q2 = pp[2];
        float Al = q0.x, Bl = q0.y, cl = q0.z, hdl = q0.w;
        float wl = q1.x, phl = q1.y;
        float Aa = q1.z, Ba = q1.w, ca = q2.x, hda = q2.y, wa = q2.z, pha = q2.w;
        if (!vs) { cl = 0.f; ca = 0.f; }

        int tb = P0 - s;                  // t at tile slot i=0
        int u  = max(tb - 1, 0);          // seed pair at x(u), x(u-1)
        float fu = (float)u;
        float el  = __expf(-hdl * fu) * cl;
        float pAl = el * __sinf(fmaf(wl, fu, phl));
        float pBl = el * rsqrtf(Bl) * __sinf(fmaf(wl, fu - 1.f, phl));
        float ea  = __expf(-hda * fu) * ca;
        float pAa = ea * __sinf(fmaf(wa, fu, pha));
        float pBa = ea * rsqrtf(Ba) * __sinf(fmaf(wa, fu - 1.f, pha));
        bool pre = (tb >= 1);             // seed applies before loop vs at t==0
        float xcl = pre ? pAl : 0.f, xpl = pre ? pBl : 0.f;
        float x0l = pre ? 0.f : pAl, xml = pre ? 0.f : pBl;
        float xca = pre ? pAa : 0.f, xpa = pre ? pBa : 0.f;
        float x0a = pre ? 0.f : pAa, xma = pre ? 0.f : pBa;

        #pragma unroll
        for (int i = 0; i < 64; ++i) {
            int t = tb + i;
            bool c0 = (t == 0);
            bool ok = ((unsigned)t) < 600u;
            float xnl = c0 ? x0l : fmaf(Al, xcl, -(Bl * xpl));
            xpl = c0 ? xml : xcl;  xcl = xnl;
            float xna = c0 ? x0a : fmaf(Aa, xca, -(Ba * xpa));
            xpa = c0 ? xma : xca;  xca = xna;
            acc[i] += ok ? (xnl + xna) : 0.f;
        }
    }

    float res = 0.f;
    #pragma unroll
    for (int i = 0; i < 64; ++i) {
        float v = acc[i];
        #pragma unroll
        for (int off = 1; off < 64; off <<= 1) v += __shfl_xor(v, off);
        if (lane == i) res = v;
    }
    out[(size_t)a * S_LEN + P0 + lane] = res;
}

// ---------------- launch ----------------
extern "C" void kernel_launch(void* const* d_in, const int* in_sizes, int n_in,
                              void* d_out, int out_size, void* d_ws, size_t ws_size,
                              hipStream_t stream)
{
    const float* x     = (const float*)d_in[0];
    const float* gamma = (const float*)d_in[1];
    const float* beta  = (const float*)d_in[2];
    const float* W     = (const float*)d_in[3];
    const float* bias  = (const float*)d_in[4];
    float* out = (float*)d_out;

    const size_t H_BYTES   = (size_t)S_LEN * DMODEL * 4;   // 16,777,216
    const size_t P_BYTES   = (size_t)S_LEN * NCOL * 4;     // 14,155,776
    const size_t PAR_BYTES = (size_t)S_LEN * NAX * 12 * 4; // 14,155,776

    char* ws = (char*)d_ws;
    float* h = (float*)ws;
    float* P = (float*)(ws + H_BYTES);
    // params aliases h when ws is tight: h is dead after k_gemm completes
    // (strict stream ordering), so k_params may overwrite it.
    float* params = (ws_size >= H_BYTES + P_BYTES + PAR_BYTES)
                        ? (float*)(ws + H_BYTES + P_BYTES)
                        : (float*)ws;

    k_layernorm<<<dim3(S_LEN), dim3(256), 0, stream>>>(x, gamma, beta, h);
    k_gemm<<<dim3((NCOL + 63) / 64, S_LEN / 128), dim3(256), 0, stream>>>(h, W, bias, P);
    k_params<<<dim3((S_LEN * NAX + 255) / 256), dim3(256), 0, stream>>>(P, params, out);
    k_scan<<<dim3(S_LEN / 64, NAX), dim3(64), 0, stream>>>(params, out);
}

// Round 2
// 140.979 us; speedup vs baseline: 1.6714x; 1.6714x over previous
//
#include <hip/hip_runtime.h>
#include <hip/hip_bf16.h>
#include <math.h>

#define S_LEN   4096
#define DMODEL  1024
#define NAX     72
#define NPAR    12
#define NCOL    864      // NPAR*NAX
#define NCOLP   896      // padded N for the GEMM (14 * 64)
#define TPROP   600
#define LN_EPS  1e-5f

typedef _Float16 half4 __attribute__((ext_vector_type(4)));
typedef _Float16 half8 __attribute__((ext_vector_type(8)));
typedef float    f32x4 __attribute__((ext_vector_type(4)));

#define GLOAD16(gp, lp)                                                        \
    __builtin_amdgcn_global_load_lds(                                          \
        (const __attribute__((address_space(1))) void*)(gp),                   \
        (__attribute__((address_space(3))) void*)(lp), 16, 0, 0)

// ---------------- Kernel 1: LayerNorm (fp32 math, fp16 output) ----------------
__global__ __launch_bounds__(256) void k_layernorm(
    const float* __restrict__ x, const float* __restrict__ gamma,
    const float* __restrict__ beta, _Float16* __restrict__ h)
{
    int row = blockIdx.x;
    int tid = threadIdx.x;
    const float4* xr = (const float4*)(x + (size_t)row * DMODEL);
    float4 v = xr[tid];
    float s  = v.x + v.y + v.z + v.w;
    float sq = v.x*v.x + v.y*v.y + v.z*v.z + v.w*v.w;
    #pragma unroll
    for (int off = 1; off < 64; off <<= 1) {
        s  += __shfl_xor(s, off);
        sq += __shfl_xor(sq, off);
    }
    __shared__ float ls[4], lq[4];
    int wid = tid >> 6, lane = tid & 63;
    if (lane == 0) { ls[wid] = s; lq[wid] = sq; }
    __syncthreads();
    s  = ls[0] + ls[1] + ls[2] + ls[3];
    sq = lq[0] + lq[1] + lq[2] + lq[3];
    float mu  = s * (1.f / DMODEL);
    float var = sq * (1.f / DMODEL) - mu * mu;
    float rs  = rsqrtf(var + LN_EPS);
    float4 g = ((const float4*)gamma)[tid];
    float4 b = ((const float4*)beta)[tid];
    half4 o;
    o.x = (_Float16)((v.x - mu) * rs * g.x + b.x);
    o.y = (_Float16)((v.y - mu) * rs * g.y + b.y);
    o.z = (_Float16)((v.z - mu) * rs * g.z + b.z);
    o.w = (_Float16)((v.w - mu) * rs * g.w + b.w);
    ((half4*)(h + (size_t)row * DMODEL))[tid] = o;
}

// ---------------- Kernel 1b: W fp32 -> fp16, pad rows 864..895 with 0 ----------------
__global__ __launch_bounds__(256) void k_wsplit(
    const float* __restrict__ W, _Float16* __restrict__ Wf)
{
    int t = blockIdx.x * 256 + threadIdx.x;   // 114688 threads, 8 elems each
    int row = t >> 7;                          // 128 threads per 1024-row
    int c0  = (t & 127) * 8;
    half8 o;
    if (row < NCOL) {
        const float4* p = (const float4*)(W + (size_t)row * DMODEL + c0);
        float4 a = p[0], b = p[1];
        o[0]=(_Float16)a.x; o[1]=(_Float16)a.y; o[2]=(_Float16)a.z; o[3]=(_Float16)a.w;
        o[4]=(_Float16)b.x; o[5]=(_Float16)b.y; o[6]=(_Float16)b.z; o[7]=(_Float16)b.w;
    } else {
        #pragma unroll
        for (int i = 0; i < 8; ++i) o[i] = (_Float16)0.f;
    }
    *(half8*)(Wf + (size_t)row * DMODEL + c0) = o;
}

// ---------------- Kernel 2: MFMA GEMM  P = h @ W^T + b (fp16 in, fp32 out) ----------------
// BM=128 BN=64 BK=32, 256 thr = 4 waves (2x2), wave tile 64x32.
// global_load_lds staging, linear LDS + pre-swizzled global source (ch ^ ((row>>1)&3)).
__global__ __launch_bounds__(256) void k_gemm(
    const _Float16* __restrict__ A, const _Float16* __restrict__ B,
    const float* __restrict__ bias, float* __restrict__ P)
{
    __shared__ char smem[12288];           // A tile 8KB [128][32] f16, B tile 4KB [64][32]
    char* smA = smem;
    char* smB = smem + 8192;

    int tid  = threadIdx.x;
    int lane = tid & 63;
    int wid  = tid >> 6;
    int wr   = wid >> 1, wc = wid & 1;
    int n0   = blockIdx.x * 64;
    int m0   = blockIdx.y * 128;

    // staging maps (chunk = 16B = 8 fp16)
    // A: chunks q = tid and tid+256 ; q -> row=q>>2, ch=q&3, ch_g = ch ^ ((row>>1)&3)
    int qa0 = tid, qa1 = tid + 256;
    int ar0 = qa0 >> 2, ac0 = (qa0 & 3) ^ ((ar0 >> 1) & 3);
    int ar1 = qa1 >> 2, ac1 = (qa1 & 3) ^ ((ar1 >> 1) & 3);
    int br  = tid >> 2, bc  = (tid & 3) ^ ((br >> 1) & 3);
    const _Float16* gA0 = A + (size_t)(m0 + ar0) * DMODEL + ac0 * 8;
    const _Float16* gA1 = A + (size_t)(m0 + ar1) * DMODEL + ac1 * 8;
    const _Float16* gB  = B + (size_t)(n0 + br)  * DMODEL + bc  * 8;

    // fragment ds_read offsets (bytes): row*64 + (ch_orig ^ ((l>>1)&3))*16
    int fr  = lane & 15;
    int chs = ((lane >> 4) ^ ((lane >> 1) & 3)) * 16;
    int aoff[4], boff[2];
    #pragma unroll
    for (int m = 0; m < 4; ++m) aoff[m] = (wr * 64 + m * 16 + fr) * 64 + chs;
    #pragma unroll
    for (int n = 0; n < 2; ++n) boff[n] = (wc * 32 + n * 16 + fr) * 64 + chs;

    f32x4 acc[4][2];
    #pragma unroll
    for (int m = 0; m < 4; ++m)
        #pragma unroll
        for (int n = 0; n < 2; ++n) acc[m][n] = (f32x4){0.f, 0.f, 0.f, 0.f};

    for (int k0 = 0; k0 < DMODEL; k0 += 32) {
        if (k0) __syncthreads();                     // prev compute done
        GLOAD16(gA0 + k0, smA + qa0 * 16);
        GLOAD16(gA1 + k0, smA + qa1 * 16);
        GLOAD16(gB  + k0, smB + tid * 16);
        __syncthreads();                             // staging visible (vmcnt drain)

        half8 af[4], bf[2];
        #pragma unroll
        for (int m = 0; m < 4; ++m) af[m] = *(const half8*)(smA + aoff[m]);
        #pragma unroll
        for (int n = 0; n < 2; ++n) bf[n] = *(const half8*)(smB + boff[n]);
        #pragma unroll
        for (int m = 0; m < 4; ++m)
            #pragma unroll
            for (int n = 0; n < 2; ++n)
                acc[m][n] = __builtin_amdgcn_mfma_f32_16x16x32_f16(
                                af[m], bf[n], acc[m][n], 0, 0, 0);
    }

    // epilogue: D row = (l>>4)*4 + j, col = l&15
    int rb = m0 + wr * 64 + (lane >> 4) * 4;
    #pragma unroll
    for (int n = 0; n < 2; ++n) {
        int col = n0 + wc * 32 + n * 16 + fr;
        float bv = (col < NCOL) ? bias[col] : 0.f;
        #pragma unroll
        for (int m = 0; m < 4; ++m) {
            int r0 = rb + m * 16;
            #pragma unroll
            for (int j = 0; j < 4; ++j)
                P[(size_t)(r0 + j) * NCOLP + col] = acc[m][n][j] + bv;
        }
    }
}

// ---------------- Kernel 3: param transforms + tail outputs ----------------
__device__ __forceinline__ float softplus_f(float x) {
    return fmaxf(x, 0.f) + log1pf(expf(-fabsf(x)));
}

__global__ __launch_bounds__(256) void k_params(
    const float* __restrict__ P, float* __restrict__ params,
    float* __restrict__ out)
{
    int g = blockIdx.x * 256 + threadIdx.x;
    if (g >= S_LEN * NAX) return;
    int s = g / NAX, a = g - s * NAX;
    const float* pr = P + (size_t)s * NCOLP + a;
    float p0  = pr[0*NAX], p1  = pr[1*NAX], p2  = pr[2*NAX], p3  = pr[3*NAX];
    float p4  = pr[4*NAX], p5  = pr[5*NAX], p6  = pr[6*NAX], p7  = pr[7*NAX];
    float p8  = pr[8*NAX], p9  = pr[9*NAX], p10 = pr[10*NAX], p11 = pr[11*NAX];

    float d  = softplus_f(p1), hd  = 0.5f * d;
    float w  = sqrtf(softplus_f(p0));
    float A  = 2.f * expf(-hd) * cosf(w);
    float B  = expf(-d);
    float d2 = softplus_f(p3), hd2 = 0.5f * d2;
    float w2 = sqrtf(softplus_f(p2));
    float A2 = 2.f * expf(-hd2) * cosf(w2);
    float B2 = expf(-d2);

    float4* pp = (float4*)(params + ((size_t)a * S_LEN + s) * 12);
    pp[0] = make_float4(A,  B,  p4, hd);
    pp[1] = make_float4(w,  p6, A2, B2);
    pp[2] = make_float4(p5, hd2, w2, p7);

    size_t o1 = (size_t)NAX * S_LEN;
    float* o = out + (size_t)a * S_LEN + s;
    o[1*o1] = p8;
    o[2*o1] = softplus_f(p9);
    o[3*o1] = p10;
    o[4*o1] = softplus_f(p11);
}

// ---------------- Kernel 4: damped-oscillator scan + anti-diagonal sum ----------------
__global__ __launch_bounds__(64) void k_scan(
    const float* __restrict__ params, float* __restrict__ out)
{
    int a    = blockIdx.y;
    int P0   = blockIdx.x * 64;
    int lane = threadIdx.x;
    float acc[64];
    #pragma unroll
    for (int i = 0; i < 64; ++i) acc[i] = 0.f;

    const float* pbase = params + (size_t)a * S_LEN * 12;
    for (int j = 0; j < 11; ++j) {
        int s = P0 - 599 + j * 64 + lane;
        bool vs = (s >= 0) && (s <= P0 + 63);
        if (__ballot(vs) == 0ULL) continue;
        int sc = vs ? s : 0;
        const float4* pp = (const float4*)(pbase + (size_t)sc * 12);
        float4 q0 = pp[0], q1 = pp[1], q2 = pp[2];
        float Al = q0.x, Bl = q0.y, cl = q0.z, hdl = q0.w;
        float wl = q1.x, phl = q1.y;
        float Aa = q1.z, Ba = q1.w, ca = q2.x, hda = q2.y, wa = q2.z, pha = q2.w;
        if (!vs) { cl = 0.f; ca = 0.f; }

        int tb = P0 - s;                  // t at tile slot i=0
        int u  = max(tb - 1, 0);          // seed pair at x(u), x(u-1)
        float fu = (float)u;
        float el  = __expf(-hdl * fu) * cl;
        float pAl = el * __sinf(fmaf(wl, fu, phl));
        float pBl = el * rsqrtf(Bl) * __sinf(fmaf(wl, fu - 1.f, phl));
        float ea  = __expf(-hda * fu) * ca;
        float pAa = ea * __sinf(fmaf(wa, fu, pha));
        float pBa = ea * rsqrtf(Ba) * __sinf(fmaf(wa, fu - 1.f, pha));
        bool pre = (tb >= 1);             // seed applies before loop vs at t==0
        float xcl = pre ? pAl : 0.f, xpl = pre ? pBl : 0.f;
        float x0l = pre ? 0.f : pAl, xml = pre ? 0.f : pBl;
        float xca = pre ? pAa : 0.f, xpa = pre ? pBa : 0.f;
        float x0a = pre ? 0.f : pAa, xma = pre ? 0.f : pBa;

        #pragma unroll
        for (int i = 0; i < 64; ++i) {
            int t = tb + i;
            bool c0 = (t == 0);
            bool ok = ((unsigned)t) < 600u;
            float xnl = c0 ? x0l : fmaf(Al, xcl, -(Bl * xpl));
            xpl = c0 ? xml : xcl;  xcl = xnl;
            float xna = c0 ? x0a : fmaf(Aa, xca, -(Ba * xpa));
            xpa = c0 ? xma : xca;  xca = xna;
            acc[i] += ok ? (xnl + xna) : 0.f;
        }
    }

    float res = 0.f;
    #pragma unroll
    for (int i = 0; i < 64; ++i) {
        float v = acc[i];
        #pragma unroll
        for (int off = 1; off < 64; off <<= 1) v += __shfl_xor(v, off);
        if (lane == i) res = v;
    }
    out[(size_t)a * S_LEN + P0 + lane] = res;
}

// ---------------- launch ----------------
extern "C" void kernel_launch(void* const* d_in, const int* in_sizes, int n_in,
                              void* d_out, int out_size, void* d_ws, size_t ws_size,
                              hipStream_t stream)
{
    const float* x     = (const float*)d_in[0];
    const float* gamma = (const float*)d_in[1];
    const float* beta  = (const float*)d_in[2];
    const float* W     = (const float*)d_in[3];
    const float* bias  = (const float*)d_in[4];
    float* out = (float*)d_out;

    // workspace layout (28.8 MB):
    //   [0, 14.68MB)              P        f32 [4096][896]
    //   [14.68MB, 28.8MB)         params   f32 [72][4096][12]
    //     h_f16 (8.39MB) and W_f16 (1.84MB) alias the params region:
    //     they are dead before k_params writes it (strict stream order).
    const size_t P_BYTES = (size_t)S_LEN * NCOLP * 4;          // 14,680,064
    char* ws = (char*)d_ws;
    float*    Pm     = (float*)ws;
    float*    params = (float*)(ws + P_BYTES);
    _Float16* hf     = (_Float16*)(ws + P_BYTES);
    _Float16* Wf     = (_Float16*)(ws + P_BYTES + (size_t)S_LEN * DMODEL * 2);

    k_layernorm<<<dim3(S_LEN), dim3(256), 0, stream>>>(x, gamma, beta, hf);
    k_wsplit<<<dim3((NCOLP * DMODEL / 8) / 256), dim3(256), 0, stream>>>(W, Wf);
    k_gemm<<<dim3(NCOLP / 64, S_LEN / 128), dim3(256), 0, stream>>>(hf, Wf, bias, Pm);
    k_params<<<dim3((S_LEN * NAX + 255) / 256), dim3(256), 0, stream>>>(Pm, params, out);
    k_scan<<<dim3(S_LEN / 64, NAX), dim3(64), 0, stream>>>(params, out);
}

// Round 4
// 113.133 us; speedup vs baseline: 2.0828x; 1.2461x over previous
//
#include <hip/hip_runtime.h>
#include <hip/hip_bf16.h>
#include <math.h>

#define S_LEN   4096
#define DMODEL  1024
#define NAX     72
#define NPAR    12
#define NCOL    864      // NPAR*NAX
#define NCOLP   896      // padded N for the GEMM (14 * 64)
#define TPROP   600
#define LN_EPS  1e-5f

typedef _Float16 half4 __attribute__((ext_vector_type(4)));
typedef _Float16 half8 __attribute__((ext_vector_type(8)));
typedef float    f32x4  __attribute__((ext_vector_type(4)));
typedef float    f32x2  __attribute__((ext_vector_type(2)));
typedef float    f32x16 __attribute__((ext_vector_type(16)));

#define GLOAD16(gp, lp)                                                        \
    __builtin_amdgcn_global_load_lds(                                          \
        (const __attribute__((address_space(1))) void*)(gp),                   \
        (__attribute__((address_space(3))) void*)(lp), 16, 0, 0)

// ---------------- Kernel 1: LayerNorm (fp32 math, fp16 output) ----------------
__global__ __launch_bounds__(256) void k_layernorm(
    const float* __restrict__ x, const float* __restrict__ gamma,
    const float* __restrict__ beta, _Float16* __restrict__ h)
{
    int row = blockIdx.x;
    int tid = threadIdx.x;
    const float4* xr = (const float4*)(x + (size_t)row * DMODEL);
    float4 v = xr[tid];
    float s  = v.x + v.y + v.z + v.w;
    float sq = v.x*v.x + v.y*v.y + v.z*v.z + v.w*v.w;
    #pragma unroll
    for (int off = 1; off < 64; off <<= 1) {
        s  += __shfl_xor(s, off);
        sq += __shfl_xor(sq, off);
    }
    __shared__ float ls[4], lq[4];
    int wid = tid >> 6, lane = tid & 63;
    if (lane == 0) { ls[wid] = s; lq[wid] = sq; }
    __syncthreads();
    s  = ls[0] + ls[1] + ls[2] + ls[3];
    sq = lq[0] + lq[1] + lq[2] + lq[3];
    float mu  = s * (1.f / DMODEL);
    float var = sq * (1.f / DMODEL) - mu * mu;
    float rs  = rsqrtf(var + LN_EPS);
    float4 g = ((const float4*)gamma)[tid];
    float4 b = ((const float4*)beta)[tid];
    half4 o;
    o.x = (_Float16)((v.x - mu) * rs * g.x + b.x);
    o.y = (_Float16)((v.y - mu) * rs * g.y + b.y);
    o.z = (_Float16)((v.z - mu) * rs * g.z + b.z);
    o.w = (_Float16)((v.w - mu) * rs * g.w + b.w);
    ((half4*)(h + (size_t)row * DMODEL))[tid] = o;
}

// ---------------- Kernel 1b: W fp32 -> fp16, pad rows 864..895 with 0 ----------------
__global__ __launch_bounds__(256) void k_wsplit(
    const float* __restrict__ W, _Float16* __restrict__ Wf)
{
    int t = blockIdx.x * 256 + threadIdx.x;
    int row = t >> 7;
    int c0  = (t & 127) * 8;
    half8 o;
    if (row < NCOL) {
        const float4* p = (const float4*)(W + (size_t)row * DMODEL + c0);
        float4 a = p[0], b = p[1];
        o[0]=(_Float16)a.x; o[1]=(_Float16)a.y; o[2]=(_Float16)a.z; o[3]=(_Float16)a.w;
        o[4]=(_Float16)b.x; o[5]=(_Float16)b.y; o[6]=(_Float16)b.z; o[7]=(_Float16)b.w;
    } else {
        #pragma unroll
        for (int i = 0; i < 8; ++i) o[i] = (_Float16)0.f;
    }
    *(half8*)(Wf + (size_t)row * DMODEL + c0) = o;
}

// ---------------- Kernel 2: MFMA GEMM  P = h @ W^T + b ----------------
__global__ __launch_bounds__(256) void k_gemm(
    const _Float16* __restrict__ A, const _Float16* __restrict__ B,
    const float* __restrict__ bias, float* __restrict__ P)
{
    __shared__ char smem[12288];
    char* smA = smem;
    char* smB = smem + 8192;

    int tid  = threadIdx.x;
    int lane = tid & 63;
    int wid  = tid >> 6;
    int wr   = wid >> 1, wc = wid & 1;
    int n0   = blockIdx.x * 64;
    int m0   = blockIdx.y * 128;

    int qa0 = tid, qa1 = tid + 256;
    int ar0 = qa0 >> 2, ac0 = (qa0 & 3) ^ ((ar0 >> 1) & 3);
    int ar1 = qa1 >> 2, ac1 = (qa1 & 3) ^ ((ar1 >> 1) & 3);
    int br  = tid >> 2, bc  = (tid & 3) ^ ((br >> 1) & 3);
    const _Float16* gA0 = A + (size_t)(m0 + ar0) * DMODEL + ac0 * 8;
    const _Float16* gA1 = A + (size_t)(m0 + ar1) * DMODEL + ac1 * 8;
    const _Float16* gB  = B + (size_t)(n0 + br)  * DMODEL + bc  * 8;

    int fr  = lane & 15;
    int chs = ((lane >> 4) ^ ((lane >> 1) & 3)) * 16;
    int aoff[4], boff[2];
    #pragma unroll
    for (int m = 0; m < 4; ++m) aoff[m] = (wr * 64 + m * 16 + fr) * 64 + chs;
    #pragma unroll
    for (int n = 0; n < 2; ++n) boff[n] = (wc * 32 + n * 16 + fr) * 64 + chs;

    f32x4 acc[4][2];
    #pragma unroll
    for (int m = 0; m < 4; ++m)
        #pragma unroll
        for (int n = 0; n < 2; ++n) acc[m][n] = (f32x4){0.f, 0.f, 0.f, 0.f};

    for (int k0 = 0; k0 < DMODEL; k0 += 32) {
        if (k0) __syncthreads();
        GLOAD16(gA0 + k0, smA + qa0 * 16);
        GLOAD16(gA1 + k0, smA + qa1 * 16);
        GLOAD16(gB  + k0, smB + tid * 16);
        __syncthreads();

        half8 af[4], bf[2];
        #pragma unroll
        for (int m = 0; m < 4; ++m) af[m] = *(const half8*)(smA + aoff[m]);
        #pragma unroll
        for (int n = 0; n < 2; ++n) bf[n] = *(const half8*)(smB + boff[n]);
        #pragma unroll
        for (int m = 0; m < 4; ++m)
            #pragma unroll
            for (int n = 0; n < 2; ++n)
                acc[m][n] = __builtin_amdgcn_mfma_f32_16x16x32_f16(
                                af[m], bf[n], acc[m][n], 0, 0, 0);
    }

    int rb = m0 + wr * 64 + (lane >> 4) * 4;
    #pragma unroll
    for (int n = 0; n < 2; ++n) {
        int col = n0 + wc * 32 + n * 16 + fr;
        float bv = (col < NCOL) ? bias[col] : 0.f;
        #pragma unroll
        for (int m = 0; m < 4; ++m) {
            int r0 = rb + m * 16;
            #pragma unroll
            for (int j = 0; j < 4; ++j)
                P[(size_t)(r0 + j) * NCOLP + col] = acc[m][n][j] + bv;
        }
    }
}

// ---------------- Kernel 3: param transforms + tail outputs ----------------
// params layout per (axis, s): 3 x float4, packed (lin, ang) pairs:
//   pp[0] = (A_l, A_a, B_l,  B_a )
//   pp[1] = (c_l, c_a, hd_l, hd_a)   c_l=p4, c_a=p5
//   pp[2] = (w_l, w_a, ph_l, ph_a)   ph_l=p6, ph_a=p7
__device__ __forceinline__ float softplus_f(float x) {
    return fmaxf(x, 0.f) + log1pf(expf(-fabsf(x)));
}

__global__ __launch_bounds__(256) void k_params(
    const float* __restrict__ P, float* __restrict__ params,
    float* __restrict__ out)
{
    int g = blockIdx.x * 256 + threadIdx.x;
    if (g >= S_LEN * NAX) return;
    int s = g / NAX, a = g - s * NAX;
    const float* pr = P + (size_t)s * NCOLP + a;
    float p0  = pr[0*NAX], p1  = pr[1*NAX], p2  = pr[2*NAX], p3  = pr[3*NAX];
    float p4  = pr[4*NAX], p5  = pr[5*NAX], p6  = pr[6*NAX], p7  = pr[7*NAX];
    float p8  = pr[8*NAX], p9  = pr[9*NAX], p10 = pr[10*NAX], p11 = pr[11*NAX];

    float d  = softplus_f(p1), hd  = 0.5f * d;
    float w  = sqrtf(softplus_f(p0));
    float A  = 2.f * expf(-hd) * cosf(w);
    float B  = expf(-d);
    float d2 = softplus_f(p3), hd2 = 0.5f * d2;
    float w2 = sqrtf(softplus_f(p2));
    float A2 = 2.f * expf(-hd2) * cosf(w2);
    float B2 = expf(-d2);

    float4* pp = (float4*)(params + ((size_t)a * S_LEN + s) * 12);
    pp[0] = make_float4(A,   A2,  B,   B2);
    pp[1] = make_float4(p4,  p5,  hd,  hd2);   // (c_l, c_a, hd_l, hd_a)
    pp[2] = make_float4(w,   w2,  p6,  p7);    // (w_l, w_a, ph_l, ph_a)

    size_t o1 = (size_t)NAX * S_LEN;
    float* o = out + (size_t)a * S_LEN + s;
    o[1*o1] = p8;
    o[2*o1] = softplus_f(p9);
    o[3*o1] = p10;
    o[4*o1] = softplus_f(p11);
}

// ---------------- Kernel 4: damped-oscillator scan + anti-diagonal sum ----------------
// 1-D grid 4608 = 72 axes x 64 tiles, XCD chunk swizzle (each XCD: 9 whole axes).
// Per block: outputs [P0, P0+64) of one axis. Source classes:
//   j=0     : s = P0+lane (interior)  -> t==0 seed-inject, no acc mask needed
//   j=1..8  : tb = (j-1)*64+1+lane <= 512 -> pure recurrence, zero masks
//   j=9,10  : tb in [513,640] -> t<=599 acc mask; c zeroed for tb>599 / s<0
__device__ __forceinline__ f32x2 sin2(f32x2 v) {
    f32x2 r; r.x = __sinf(v.x); r.y = __sinf(v.y); return r;
}
__device__ __forceinline__ f32x2 exp2e(f32x2 v) {
    f32x2 r; r.x = __expf(v.x); r.y = __expf(v.y); return r;
}

#define OSTEP(V,K) do {                                                        \
    f32x2 xn = A2v*xc - B2v*xp; xp = xc; xc = xn;                              \
    V[K] += xn.x + xn.y; } while(0)

#define OSTEPM(V,K,IB) do {                                                    \
    f32x2 xn = A2v*xc - B2v*xp; xp = xc; xc = xn;                              \
    float hs = xn.x + xn.y;                                                    \
    V[K] += (((IB)+(K)) <= iLim) ? hs : 0.f; } while(0)

#define OSTEP0(V,K,IB) do {                                                    \
    bool c0 = (((IB)+(K)) == lane);                                            \
    f32x2 xn = A2v*xc - B2v*xp;                                                \
    xn = c0 ? x0 : xn;                                                         \
    f32x2 xq = c0 ? xm1 : xc;                                                  \
    xp = xq; xc = xn;                                                          \
    V[K] += xn.x + xn.y; } while(0)

#define RUN4(STEPM)                                                            \
    { _Pragma("unroll") for (int k2=0;k2<16;++k2) STEPM(acc0,k2,0);            \
      _Pragma("unroll") for (int k2=0;k2<16;++k2) STEPM(acc1,k2,16);           \
      _Pragma("unroll") for (int k2=0;k2<16;++k2) STEPM(acc2,k2,32);           \
      _Pragma("unroll") for (int k2=0;k2<16;++k2) STEPM(acc3,k2,48); }

#define OSTEP_NOIB(V,K,IB) OSTEP(V,K)

__global__ __launch_bounds__(64) void k_scan(
    const float* __restrict__ params, float* __restrict__ out)
{
    int bid  = blockIdx.x;
    int swz  = (bid & 7) * 576 + (bid >> 3);   // 4608 = 8 * 576, bijective
    int a    = swz >> 6;
    int P0   = (swz & 63) * 64;
    int lane = threadIdx.x;

    f32x16 acc0 = {}, acc1 = {}, acc2 = {}, acc3 = {};

    const float* pbase = params + (size_t)a * S_LEN * 12;

    // ---- j = 0: interior sources ----
    {
        int s = P0 + lane;
        const float4* pp = (const float4*)(pbase + (size_t)s * 12);
        float4 q0 = pp[0], q1 = pp[1], q2 = pp[2];
        f32x2 A2v = {q0.x, q0.y}, B2v = {q0.z, q0.w};
        f32x2 c2  = {q1.x, q1.y};
        f32x2 w2v = {q2.x, q2.y}, ph2 = {q2.z, q2.w};
        f32x2 ehd; ehd.x = rsqrtf(B2v.x); ehd.y = rsqrtf(B2v.y);
        f32x2 x0  = c2 * sin2(ph2);              // x(0)
        f32x2 xm1 = c2 * ehd * sin2(ph2 - w2v);  // x(-1)
        f32x2 xc = {0.f, 0.f}, xp = {0.f, 0.f};
        RUN4(OSTEP0)
    }

    // ---- j = 1..10: exterior sources ----
    for (int j = 1; j <= 10; ++j) {
        int tbl = (j - 1) * 64 + 1;
        if (tbl > P0) break;                    // uniform: no valid lane
        int tb = tbl + lane;
        int s  = P0 - tb;
        bool ok = (s >= 0) && (tb <= 599);
        int sc = ok ? s : 0;
        const float4* pp = (const float4*)(pbase + (size_t)sc * 12);
        float4 q0 = pp[0], q1 = pp[1], q2 = pp[2];
        f32x2 A2v = {q0.x, q0.y}, B2v = {q0.z, q0.w};
        f32x2 c2  = {q1.x, q1.y}, hd2 = {q1.z, q1.w};
        f32x2 w2v = {q2.x, q2.y}, ph2 = {q2.z, q2.w};
        if (!ok) { c2.x = 0.f; c2.y = 0.f; }
        f32x2 ehd; ehd.x = rsqrtf(B2v.x); ehd.y = rsqrtf(B2v.y);
        float fu = (float)(tb - 1);
        f32x2 e2 = c2 * exp2e(-hd2 * fu);
        f32x2 s1 = w2v * fu + ph2;
        f32x2 xc = e2 * sin2(s1);                // x(tb-1)
        f32x2 xp = e2 * ehd * sin2(s1 - w2v);    // x(tb-2)

        if (j <= 8) {
            RUN4(OSTEP_NOIB)
        } else {
            int iLim = 599 - tb;
            RUN4(OSTEPM)
        }
    }

    // ---- cross-lane reduce: out[P0+i] = sum over lanes of acc[i] ----
    float res = 0.f;
    #pragma unroll
    for (int k = 0; k < 16; ++k) {
        float v = acc0[k];
        #pragma unroll
        for (int off = 1; off < 64; off <<= 1) v += __shfl_xor(v, off);
        if (lane == k) res = v;
    }
    #pragma unroll
    for (int k = 0; k < 16; ++k) {
        float v = acc1[k];
        #pragma unroll
        for (int off = 1; off < 64; off <<= 1) v += __shfl_xor(v, off);
        if (lane == 16 + k) res = v;
    }
    #pragma unroll
    for (int k = 0; k < 16; ++k) {
        float v = acc2[k];
        #pragma unroll
        for (int off = 1; off < 64; off <<= 1) v += __shfl_xor(v, off);
        if (lane == 32 + k) res = v;
    }
    #pragma unroll
    for (int k = 0; k < 16; ++k) {
        float v = acc3[k];
        #pragma unroll
        for (int off = 1; off < 64; off <<= 1) v += __shfl_xor(v, off);
        if (lane == 48 + k) res = v;
    }
    out[(size_t)a * S_LEN + P0 + lane] = res;
}

// ---------------- launch ----------------
extern "C" void kernel_launch(void* const* d_in, const int* in_sizes, int n_in,
                              void* d_out, int out_size, void* d_ws, size_t ws_size,
                              hipStream_t stream)
{
    const float* x     = (const float*)d_in[0];
    const float* gamma = (const float*)d_in[1];
    const float* beta  = (const float*)d_in[2];
    const float* W     = (const float*)d_in[3];
    const float* bias  = (const float*)d_in[4];
    float* out = (float*)d_out;

    const size_t P_BYTES = (size_t)S_LEN * NCOLP * 4;          // 14,680,064
    char* ws = (char*)d_ws;
    float*    Pm     = (float*)ws;
    float*    params = (float*)(ws + P_BYTES);
    _Float16* hf     = (_Float16*)(ws + P_BYTES);
    _Float16* Wf     = (_Float16*)(ws + P_BYTES + (size_t)S_LEN * DMODEL * 2);

    k_layernorm<<<dim3(S_LEN), dim3(256), 0, stream>>>(x, gamma, beta, hf);
    k_wsplit<<<dim3((NCOLP * DMODEL / 8) / 256), dim3(256), 0, stream>>>(W, Wf);
    k_gemm<<<dim3(NCOLP / 64, S_LEN / 128), dim3(256), 0, stream>>>(hf, Wf, bias, Pm);
    k_params<<<dim3((S_LEN * NAX + 255) / 256), dim3(256), 0, stream>>>(Pm, params, out);
    k_scan<<<dim3(S_LEN / 64 * NAX), dim3(64), 0, stream>>>(params, out);
}